// Round 3
// baseline (216.620 us; speedup 1.0000x reference)
//
#include <hip/hip_runtime.h>

#define NJ 24
#define ROWF 99            // 24*4 quats + 3 pos
#define BS 64
#define TT 2048
#define NROWS (BS * TT)    // 131072
#define TROWS 64           // rows per block
#define BLOCK 256          // 4 threads per row: bit0 = X/Y, bit1 = segA/segB
#define NBLOCKS (NROWS / TROWS)  // 2048

#define M_FRESH 0
#define M_NORM  1
#define M_LEAF  2          // T update only (G dead after this step)
#define M_RSTA  3          // segA resets to anchor-relative identity, segB continues
#define M_RSTB  4          // segB resets, segA continues

__device__ __forceinline__ void quat2mat(float w, float x, float y, float z, float* R) {
  float s = 2.0f / (w*w + x*x + y*y + z*z);      // matches reference (unnormalized q)
  float xx = s*x*x, yy = s*y*y, zz = s*z*z;
  float xy = s*x*y, xz = s*x*z, yz = s*y*z;
  float xw = s*x*w, yw = s*y*w, zw = s*z*w;
  R[0] = 1.0f - (yy+zz); R[1] = xy - zw;        R[2] = xz + yw;
  R[3] = xy + zw;        R[4] = 1.0f - (xx+zz); R[5] = yz - xw;
  R[6] = xz - yw;        R[7] = yz + xw;        R[8] = 1.0f - (xx+yy);
}

__device__ __forceinline__ void mm3(const float* A, const float* B, float* C) {
#pragma unroll
  for (int r = 0; r < 3; ++r)
#pragma unroll
    for (int c = 0; c < 3; ++c)
      C[3*r+c] = fmaf(A[3*r], B[c], fmaf(A[3*r+1], B[3+c], A[3*r+2]*B[6+c]));
}

// Scan step: lane-varying joint index (CA for segA, CB for segB), uniform instrs.
// Maintains running affine (G, T0..T2) relative to the segment anchor; stores
// relative translation into trel[S]; accumulates quat MSE vs the X/Y partner.
#define SCAN_STEP(S, CA, CB, MODE) do {                                        \
  const int c_ = seg ? (CB) : (CA);                                            \
  const float* qp_ = rowp + 4*c_;                                              \
  float q0_ = qp_[0], q1_ = qp_[1], q2_ = qp_[2], q3_ = qp_[3];                \
  { float n_  = sqrtf(q0_*q0_ + q1_*q1_ + q2_*q2_ + q3_*q3_);                  \
    float iv_ = 1.0f / fmaxf(n_, 1e-12f);                                      \
    float a0_ = q0_*iv_, a1_ = q1_*iv_, a2_ = q2_*iv_, a3_ = q3_*iv_;          \
    float d0_ = a0_ - __shfl_xor(a0_, 1, 64);                                  \
    float d1_ = a1_ - __shfl_xor(a1_, 1, 64);                                  \
    float d2_ = a2_ - __shfl_xor(a2_, 1, 64);                                  \
    float d3_ = a3_ - __shfl_xor(a3_, 1, 64);                                  \
    rot_acc += d0_*d0_ + d1_*d1_ + d2_*d2_ + d3_*d3_; }                        \
  float R_[9]; quat2mat(q0_, q1_, q2_, q3_, R_);                               \
  const float* vp_ = ((S) == 0) ? vbase0 : (tvp + 3*c_);                       \
  float v0_ = vp_[0], v1_ = vp_[1], v2_ = vp_[2];                              \
  if ((MODE) == M_FRESH) {                                                     \
    _Pragma("unroll") for (int i_ = 0; i_ < 9; ++i_) G[i_] = R_[i_];           \
    T0 = v0_; T1 = v1_; T2 = v2_;                                              \
  } else {                                                                     \
    float Tn0_ = fmaf(G[0], v0_, fmaf(G[1], v1_, fmaf(G[2], v2_, T0)));        \
    float Tn1_ = fmaf(G[3], v0_, fmaf(G[4], v1_, fmaf(G[5], v2_, T1)));        \
    float Tn2_ = fmaf(G[6], v0_, fmaf(G[7], v1_, fmaf(G[8], v2_, T2)));        \
    if ((MODE) == M_LEAF) { T0 = Tn0_; T1 = Tn1_; T2 = Tn2_; }                 \
    else {                                                                     \
      float Gn_[9]; mm3(G, R_, Gn_);                                           \
      if ((MODE) == M_NORM) {                                                  \
        _Pragma("unroll") for (int i_ = 0; i_ < 9; ++i_) G[i_] = Gn_[i_];      \
        T0 = Tn0_; T1 = Tn1_; T2 = Tn2_;                                       \
      } else {                                                                 \
        bool rst_ = ((MODE) == M_RSTA) ? (seg == 0) : (seg == 1);              \
        _Pragma("unroll") for (int i_ = 0; i_ < 9; ++i_)                       \
          G[i_] = rst_ ? R_[i_] : Gn_[i_];                                     \
        T0 = rst_ ? v0_ : Tn0_; T1 = rst_ ? v1_ : Tn1_; T2 = rst_ ? v2_ : Tn2_;\
      }                                                                        \
    }                                                                          \
  }                                                                            \
  trel[S][0] = T0; trel[S][1] = T1; trel[S][2] = T2;                           \
} while (0)

// Tail step: global T = anchor ∘ trel, then X/Y squared diff.
#define TAIL_STEP(S, AG, AT) do {                                              \
  float g0_ = fmaf(AG[0], trel[S][0], fmaf(AG[1], trel[S][1],                  \
              fmaf(AG[2], trel[S][2], AT[0])));                                \
  float g1_ = fmaf(AG[3], trel[S][0], fmaf(AG[4], trel[S][1],                  \
              fmaf(AG[5], trel[S][2], AT[1])));                                \
  float g2_ = fmaf(AG[6], trel[S][0], fmaf(AG[7], trel[S][1],                  \
              fmaf(AG[8], trel[S][2], AT[2])));                                \
  float e0_ = g0_ - __shfl_xor(g0_, 1, 64);                                    \
  float e1_ = g1_ - __shfl_xor(g1_, 1, 64);                                    \
  float e2_ = g2_ - __shfl_xor(g2_, 1, 64);                                    \
  float d2_ = e0_*e0_ + e1_*e1_ + e2_*e2_;                                     \
  gacc += d2_;                                                                 \
  if ((S) == 0) pos_d2 = d2_;                                                  \
} while (0)

__global__ __launch_bounds__(BLOCK, 3) void motion_loss_kernel(
    const float* __restrict__ Ym, const float* __restrict__ Xm,
    const float* __restrict__ Yt, const float* __restrict__ Xt,
    float* __restrict__ out) {
  __shared__ __align__(16) float tileX[TROWS * ROWF];   // 25,344 B
  __shared__ __align__(16) float tileY[TROWS * ROWF];   // 25,344 B
  __shared__ float tvX[NJ * 3], tvY[NJ * 3];            // total 51,264 B -> 3 blocks/CU

  const int tid = threadIdx.x;
  const int blk = blockIdx.x;
  const size_t row0 = (size_t)blk * TROWS;              // 64 | 2048 -> single batch
  const int b = (int)(row0 >> 11);

  // ---- Staging: batched register prefetch (deep MLP), then LDS writes ----
  const float4* gx = (const float4*)(Xm + row0 * ROWF); // base = blk*25344 B, 16B-aligned
  const float4* gy = (const float4*)(Ym + row0 * ROWF);
  float4 rx[6], ry[6];
  float4 rtx = {0,0,0,0}, rty = {0,0,0,0};
#pragma unroll
  for (int k = 0; k < 6; ++k) rx[k] = gx[k * BLOCK + tid];
#pragma unroll
  for (int k = 0; k < 6; ++k) ry[k] = gy[k * BLOCK + tid];
  const bool tail48 = (tid < (TROWS * ROWF / 4 - 6 * BLOCK));  // 1584-1536 = 48
  if (tail48) { rtx = gx[6 * BLOCK + tid]; rty = gy[6 * BLOCK + tid]; }
  float tvv = 0.0f;
  if (tid < 72) tvv = Xt[(size_t)b * 72 + tid];
  else if (tid < 144) tvv = Yt[(size_t)b * 72 + (tid - 72)];

  float4* lx4 = (float4*)tileX;
  float4* ly4 = (float4*)tileY;
#pragma unroll
  for (int k = 0; k < 6; ++k) lx4[k * BLOCK + tid] = rx[k];
#pragma unroll
  for (int k = 0; k < 6; ++k) ly4[k * BLOCK + tid] = ry[k];
  if (tail48) { lx4[6 * BLOCK + tid] = rtx; ly4[6 * BLOCK + tid] = rty; }
  if (tid < 72) tvX[tid] = tvv;
  else if (tid < 144) tvY[tid - 72] = tvv;
  __syncthreads();

  // ---- Role mapping: bit0 = X/Y (par), bit1 = segA/segB (seg), bits2+ = row ----
  const int par = tid & 1;
  const int seg = (tid >> 1) & 1;
  const int rl  = tid >> 2;                       // 0..63; partners stay in-wave
  const float* __restrict__ rowp = (par ? tileY : tileX) + rl * ROWF;
  const float* __restrict__ tvp  = par ? tvY : tvX;
  // step 0: segA local translation = root position (row floats 96..98); segB = tv[13]
  const float* vbase0 = seg ? (tvp + 3 * 13) : (rowp + 96);

  float rot_acc = 0.0f, gacc = 0.0f, pos_d2 = 0.0f;
  float G[9], T0, T1, T2;
  float trel[12][3];

  // TOPOLOGY = [-1,0,0,0,1,2,3,4,5,6,7,8,9,9,9,12,13,14,16,17,18,19,20,21]
  // segA chains (anchor: step0-4 identity-with-root, step5-11 A0=(R0,pos)):
  //   [0,1,4,7,10 | 2,5,8,11 | 3,6,9]
  // segB chains (anchor: A9, received via shfl): [13,16,18,20,22 | 14,17,19,21,23 | 12,15]
  SCAN_STEP(0,  0, 13, M_FRESH);
  float A0G[9], A0T[3];                            // A0 snapshot (meaningful on segA lanes)
#pragma unroll
  for (int i = 0; i < 9; ++i) A0G[i] = G[i];
  A0T[0] = T0; A0T[1] = T1; A0T[2] = T2;
  SCAN_STEP(1,  1, 16, M_NORM);
  SCAN_STEP(2,  4, 18, M_NORM);
  SCAN_STEP(3,  7, 20, M_NORM);
  SCAN_STEP(4, 10, 22, M_LEAF);                    // both joints are leaves: skip G update
  SCAN_STEP(5,  2, 14, M_FRESH);
  SCAN_STEP(6,  5, 17, M_NORM);
  SCAN_STEP(7,  8, 19, M_NORM);
  SCAN_STEP(8, 11, 21, M_NORM);
  SCAN_STEP(9,  3, 23, M_RSTA);                    // segA: joint 3 restarts from A0
  SCAN_STEP(10, 6, 12, M_RSTB);                    // segB: joint 12 restarts from A9
  SCAN_STEP(11, 9, 15, M_NORM);

  // A9 = A0 ∘ (running affine of spine [3,6,9]) — valid on segA lanes only
  float A9G[9], A9T[3];
  mm3(A0G, G, A9G);
  A9T[0] = fmaf(A0G[0], T0, fmaf(A0G[1], T1, fmaf(A0G[2], T2, A0T[0])));
  A9T[1] = fmaf(A0G[3], T0, fmaf(A0G[4], T1, fmaf(A0G[5], T2, A0T[1])));
  A9T[2] = fmaf(A0G[6], T0, fmaf(A0G[7], T1, fmaf(A0G[8], T2, A0T[2])));

  // Exchange: segB lanes receive A9 from their segA partner (lane ^ 2, same par)
  float A1G[9], A1T[3], A2G[9], A2T[3];
#pragma unroll
  for (int i = 0; i < 9; ++i) {
    float r = __shfl_xor(A9G[i], 2, 64);
    float idv = (i == 0 || i == 4 || i == 8) ? 1.0f : 0.0f;
    A2G[i] = seg ? r : A0G[i];
    A1G[i] = seg ? r : idv;
  }
#pragma unroll
  for (int i = 0; i < 3; ++i) {
    float r = __shfl_xor(A9T[i], 2, 64);
    A2T[i] = seg ? r : A0T[i];
    A1T[i] = seg ? r : 0.0f;
  }

  // Tail: globalize + X/Y gtr diffs (steps 0-4 anchor A1, steps 5-11 anchor A2)
  TAIL_STEP(0,  A1G, A1T);
  TAIL_STEP(1,  A1G, A1T);
  TAIL_STEP(2,  A1G, A1T);
  TAIL_STEP(3,  A1G, A1T);
  TAIL_STEP(4,  A1G, A1T);
  TAIL_STEP(5,  A2G, A2T);
  TAIL_STEP(6,  A2G, A2T);
  TAIL_STEP(7,  A2G, A2T);
  TAIL_STEP(8,  A2G, A2T);
  TAIL_STEP(9,  A2G, A2T);
  TAIL_STEP(10, A2G, A2T);
  TAIL_STEP(11, A2G, A2T);

  const float c_rot = 1.0f / ((float)NROWS * NJ * 4);   // B1 * mean over (bs,T,24,4)
  const float c_gtr = 2.5f / ((float)NROWS * NJ * 3);   // B2*2.5 * mean over (bs,T,24,3)
  const float c_pos = 1.0f / ((float)NROWS * 3);        // B2 * mean over (bs,T,3)
  float posw = seg ? 0.0f : 1.0f;                       // pos term: segA lanes only
  // 0.5: X/Y lane pairs accumulate identical squared diffs
  float contrib = 0.5f * (c_rot * rot_acc + c_gtr * gacc + c_pos * pos_d2 * posw);
#pragma unroll
  for (int o = 32; o > 0; o >>= 1) contrib += __shfl_down(contrib, o, 64);
  if ((tid & 63) == 0) atomicAdd(out, contrib);
}

extern "C" void kernel_launch(void* const* d_in, const int* in_sizes, int n_in,
                              void* d_out, int out_size, void* d_ws, size_t ws_size,
                              hipStream_t stream) {
  const float* Ym = (const float*)d_in[0];
  const float* Xm = (const float*)d_in[1];
  const float* Yt = (const float*)d_in[2];
  const float* Xt = (const float*)d_in[3];
  float* out = (float*)d_out;
  hipMemsetAsync(out, 0, sizeof(float), stream);
  motion_loss_kernel<<<NBLOCKS, BLOCK, 0, stream>>>(Ym, Xm, Yt, Xt, out);
}

// Round 4
// 175.926 us; speedup vs baseline: 1.2313x; 1.2313x over previous
//
#include <hip/hip_runtime.h>

#define NJ 24
#define ROWF 99            // 24*4 quats + 3 pos
#define BS 64
#define TT 2048
#define NROWS (BS * TT)    // 131072
#define TROWS 32           // rows per block (32 | 2048 -> tile never spans batches)
#define BLOCK 64           // one wave; 2 lanes per row: even=X chain, odd=Y chain
#define NBLOCKS (NROWS / TROWS)   // 4096
#define TILE4 (TROWS * ROWF / 4)  // 792 float4 per array

__device__ __forceinline__ void quat2mat(float w, float x, float y, float z, float* R) {
  float s = 2.0f / (w*w + x*x + y*y + z*z);      // matches reference (unnormalized q)
  float xx = s*x*x, yy = s*y*y, zz = s*z*z;
  float xy = s*x*y, xz = s*x*z, yz = s*y*z;
  float xw = s*x*w, yw = s*y*w, zw = s*z*w;
  R[0] = 1.0f - (yy+zz); R[1] = xy - zw;        R[2] = xz + yw;
  R[3] = xy + zw;        R[4] = 1.0f - (xx+zz); R[5] = yz - xw;
  R[6] = xz - yw;        R[7] = yz + xw;        R[8] = 1.0f - (xx+yy);
}

__device__ __forceinline__ void mm3(const float* A, const float* B, float* C) {
#pragma unroll
  for (int r = 0; r < 3; ++r)
#pragma unroll
    for (int c = 0; c < 3; ++c)
      C[3*r+c] = fmaf(A[3*r], B[c], fmaf(A[3*r+1], B[3+c], A[3*r+2]*B[6+c]));
}

// normalized-quat squared diff vs X/Y partner lane (lane^1); both lanes get the
// same d^2, compensated by the global 0.5 factor at the end
#define QMSE(q0, q1, q2, q3) ({ \
  float _n  = sqrtf((q0)*(q0) + (q1)*(q1) + (q2)*(q2) + (q3)*(q3)); \
  float _iv = 1.0f / fmaxf(_n, 1e-12f); \
  float _a0 = (q0)*_iv, _a1 = (q1)*_iv, _a2 = (q2)*_iv, _a3 = (q3)*_iv; \
  float _d0 = _a0 - __shfl_xor(_a0, 1, 64); \
  float _d1 = _a1 - __shfl_xor(_a1, 1, 64); \
  float _d2 = _a2 - __shfl_xor(_a2, 1, 64); \
  float _d3 = _a3 - __shfl_xor(_a3, 1, 64); \
  _d0*_d0 + _d1*_d1 + _d2*_d2 + _d3*_d3; })

#define TDIFF(t0, t1, t2) ({ \
  float _e0 = (t0) - __shfl_xor((t0), 1, 64); \
  float _e1 = (t1) - __shfl_xor((t1), 1, 64); \
  float _e2 = (t2) - __shfl_xor((t2), 1, 64); \
  _e0*_e0 + _e1*_e1 + _e2*_e2; })

// internal joint: quat MSE + rotate-accumulate + translate + gtr diff (LDS reads)
#define STEP(c, GP, TP, GO, TO) do { \
  float q0 = rowp[4*(c)], q1 = rowp[4*(c)+1], q2 = rowp[4*(c)+2], q3 = rowp[4*(c)+3]; \
  rot_acc += QMSE(q0, q1, q2, q3); \
  float R[9]; quat2mat(q0, q1, q2, q3, R); \
  mm3(GP, R, GO); \
  float v0 = tv[3*(c)], v1 = tv[3*(c)+1], v2 = tv[3*(c)+2]; \
  TO[0] = fmaf(GP[0], v0, fmaf(GP[1], v1, fmaf(GP[2], v2, TP[0]))); \
  TO[1] = fmaf(GP[3], v0, fmaf(GP[4], v1, fmaf(GP[5], v2, TP[1]))); \
  TO[2] = fmaf(GP[6], v0, fmaf(GP[7], v1, fmaf(GP[8], v2, TP[2]))); \
  gacc += TDIFF(TO[0], TO[1], TO[2]); \
} while (0)

// leaf joint: global rotation never feeds the loss -> skip quat2mat/mm3
#define LEAF(c, GP, TP) do { \
  float q0 = rowp[4*(c)], q1 = rowp[4*(c)+1], q2 = rowp[4*(c)+2], q3 = rowp[4*(c)+3]; \
  rot_acc += QMSE(q0, q1, q2, q3); \
  float v0 = tv[3*(c)], v1 = tv[3*(c)+1], v2 = tv[3*(c)+2]; \
  float t0 = fmaf(GP[0], v0, fmaf(GP[1], v1, fmaf(GP[2], v2, TP[0]))); \
  float t1 = fmaf(GP[3], v0, fmaf(GP[4], v1, fmaf(GP[5], v2, TP[1]))); \
  float t2 = fmaf(GP[6], v0, fmaf(GP[7], v1, fmaf(GP[8], v2, TP[2]))); \
  gacc += TDIFF(t0, t1, t2); \
} while (0)

__global__ __launch_bounds__(BLOCK, 2) void motion_loss_kernel(
    const float* __restrict__ Ym, const float* __restrict__ Xm,
    const float* __restrict__ Yt, const float* __restrict__ Xt,
    float* __restrict__ out) {
  // wave-private tiles: 2*3168 + 144 floats = 25,920 B -> 6 blocks/CU
  __shared__ __align__(16) float tX[TROWS * ROWF];
  __shared__ __align__(16) float tY[TROWS * ROWF];
  __shared__ float tvX[NJ * 3], tvY[NJ * 3];

  const int lane = threadIdx.x;
  const int blk = blockIdx.x;
  const size_t row0 = (size_t)blk * TROWS;
  const int b = (int)(row0 >> 11);                 // row0 / TT

  // ---- coalesced staging: global float4 -> registers (batched) -> LDS ----
  const float4* gx = (const float4*)(Xm + row0 * ROWF);  // blk*12672 B, 16B-aligned
  const float4* gy = (const float4*)(Ym + row0 * ROWF);
  float4* lx4 = (float4*)tX;
  float4* ly4 = (float4*)tY;
  {
    float4 r0[6], r1[6];
#pragma unroll
    for (int k = 0; k < 6; ++k) r0[k] = gx[k * BLOCK + lane];
#pragma unroll
    for (int k = 0; k < 6; ++k) r1[k] = gy[k * BLOCK + lane];
#pragma unroll
    for (int k = 0; k < 6; ++k) lx4[k * BLOCK + lane] = r0[k];
#pragma unroll
    for (int k = 0; k < 6; ++k) ly4[k * BLOCK + lane] = r1[k];
#pragma unroll
    for (int k = 0; k < 6; ++k) r0[k] = gx[(6 + k) * BLOCK + lane];
#pragma unroll
    for (int k = 0; k < 6; ++k) r1[k] = gy[(6 + k) * BLOCK + lane];
#pragma unroll
    for (int k = 0; k < 6; ++k) lx4[(6 + k) * BLOCK + lane] = r0[k];
#pragma unroll
    for (int k = 0; k < 6; ++k) ly4[(6 + k) * BLOCK + lane] = r1[k];
    if (lane < TILE4 - 12 * BLOCK) {               // 792 - 768 = 24 tail float4
      lx4[12 * BLOCK + lane] = gx[12 * BLOCK + lane];
      ly4[12 * BLOCK + lane] = gy[12 * BLOCK + lane];
    }
  }
#pragma unroll
  for (int k = 0; k < 3; ++k) {                    // 144 tv floats, 64 lanes
    int id = k * BLOCK + lane;
    if (id < 72) tvX[id] = Xt[(size_t)b * 72 + id];
    else if (id < 144) tvY[id - 72] = Yt[(size_t)b * 72 + (id - 72)];
  }
  __syncthreads();                                 // single-wave block: near-free

  // ---- roles: bit0 = X/Y, bits1+ = row. Bank math: array offset 3168 ≡ 0 and
  // row stride 99 ≡ 3 (mod 32) -> every LDS read is exactly 2 lanes/bank (free).
  const int par = lane & 1;
  const int rl  = lane >> 1;                       // 0..31
  const float* __restrict__ rowp = (par ? tY : tX) + rl * ROWF;
  const float* __restrict__ tv   = par ? tvY : tvX;

  float rot_acc = 0.0f, gacc = 0.0f;
  float GA[9], GB[9], GC[9], GD[9];
  float TA[3], TB[3], TC[3], TD[3];

  // root: gtr0 == raw position; feeds both the gtr term and the pos term
  {
    float q0 = rowp[0], q1 = rowp[1], q2 = rowp[2], q3 = rowp[3];
    rot_acc += QMSE(q0, q1, q2, q3);
    quat2mat(q0, q1, q2, q3, GA);
  }
  TA[0] = rowp[96]; TA[1] = rowp[97]; TA[2] = rowp[98];
  float rootd2 = TDIFF(TA[0], TA[1], TA[2]);
  gacc += rootd2;

  // BFS order, 4-slot sliding register window (verified exact in round 2).
  // TOPOLOGY = [-1,0,0,0,1,2,3,4,5,6,7,8,9,9,9,12,13,14,16,17,18,19,20,21]
  STEP(1,  GA, TA, GB, TB);
  STEP(2,  GA, TA, GC, TC);
  STEP(3,  GA, TA, GD, TD);
  STEP(4,  GB, TB, GA, TA);
  STEP(5,  GC, TC, GB, TB);
  STEP(6,  GD, TD, GC, TC);
  STEP(7,  GA, TA, GD, TD);
  STEP(8,  GB, TB, GA, TA);
  STEP(9,  GC, TC, GB, TB);
  LEAF(10, GD, TD);
  LEAF(11, GA, TA);
  STEP(12, GB, TB, GC, TC);
  STEP(13, GB, TB, GD, TD);
  STEP(14, GB, TB, GA, TA);
  LEAF(15, GC, TC);
  STEP(16, GD, TD, GB, TB);
  STEP(17, GA, TA, GC, TC);
  STEP(18, GB, TB, GD, TD);
  STEP(19, GC, TC, GA, TA);
  STEP(20, GD, TD, GB, TB);
  STEP(21, GA, TA, GC, TC);
  LEAF(22, GB, TB);
  LEAF(23, GC, TC);

  const float c_rot = 1.0f / ((float)NROWS * NJ * 4);   // B1 * mean over (bs,T,24,4)
  const float c_gtr = 2.5f / ((float)NROWS * NJ * 3);   // B2*2.5 * mean over (bs,T,24,3)
  const float c_pos = 1.0f / ((float)NROWS * 3);        // B2 * mean over (bs,T,3)
  // 0.5: X/Y lane pairs accumulate identical squared diffs
  float contrib = 0.5f * (c_rot * rot_acc + c_gtr * gacc + c_pos * rootd2);
#pragma unroll
  for (int o = 32; o > 0; o >>= 1) contrib += __shfl_down(contrib, o, 64);
  if (lane == 0) atomicAdd(out, contrib);
}

extern "C" void kernel_launch(void* const* d_in, const int* in_sizes, int n_in,
                              void* d_out, int out_size, void* d_ws, size_t ws_size,
                              hipStream_t stream) {
  const float* Ym = (const float*)d_in[0];
  const float* Xm = (const float*)d_in[1];
  const float* Yt = (const float*)d_in[2];
  const float* Xt = (const float*)d_in[3];
  float* out = (float*)d_out;
  hipMemsetAsync(out, 0, sizeof(float), stream);
  motion_loss_kernel<<<NBLOCKS, BLOCK, 0, stream>>>(Ym, Xm, Yt, Xt, out);
}